// Round 3
// baseline (953.288 us; speedup 1.0000x reference)
//
#include <hip/hip_runtime.h>

#define NN 50000
#define NE 800000

typedef unsigned int uint32;
typedef unsigned short ushort16;

__device__ __forceinline__ float wave_sum(float v) {
#pragma unroll
  for (int off = 32; off > 0; off >>= 1) v += __shfl_xor(v, off, 64);
  return v;
}
__device__ __forceinline__ float bfl(uint32 u) {  // low bf16 of packed word
  union { uint32 u; float f; } c; c.u = u << 16; return c.f;
}
__device__ __forceinline__ float bfh(uint32 u) {  // high bf16 of packed word
  union { uint32 u; float f; } c; c.u = u & 0xffff0000u; return c.f;
}
__device__ __forceinline__ ushort16 f2bf(float f) {  // RNE pack (finite values)
  union { float f; uint32 u; } c; c.f = f;
  uint32 r = c.u + 0x7fffu + ((c.u >> 16) & 1u);
  return (ushort16)(r >> 16);
}

// ---------------- CSR build ----------------
__global__ void zero_int_kernel(int* __restrict__ p, int n) {
  int i = blockIdx.x * blockDim.x + threadIdx.x;
  if (i < n) p[i] = 0;
}

__global__ void count_kernel(const int* __restrict__ dst, int* __restrict__ deg) {
  int e = blockIdx.x * blockDim.x + threadIdx.x;
  if (e < NE) atomicAdd(&deg[dst[e]], 1);
}

__global__ __launch_bounds__(1024) void scan_kernel(const int* __restrict__ deg,
                                                    int* __restrict__ rowptr,
                                                    int* __restrict__ cursor) {
  __shared__ int part[1024];
  const int t = threadIdx.x;
  const int chunk = (NN + 1023) / 1024;
  const int lo = min(t * chunk, NN);
  const int hi = min(lo + chunk, NN);
  int sum = 0;
  for (int i = lo; i < hi; ++i) sum += deg[i];
  part[t] = sum;
  __syncthreads();
  for (int off = 1; off < 1024; off <<= 1) {
    int mine = part[t];
    int add = (t >= off) ? part[t - off] : 0;
    __syncthreads();
    part[t] = mine + add;
    __syncthreads();
  }
  int base = (t > 0) ? part[t - 1] : 0;
  for (int i = lo; i < hi; ++i) {
    rowptr[i] = base;
    cursor[i] = base;
    base += deg[i];
  }
  if (t == 0) rowptr[NN] = part[1023];
}

// scatter edges into CSR order; edge_attr reordered AND packed to bf16 (16B/edge)
__global__ void scatter_kernel(const int* __restrict__ src, const int* __restrict__ dst,
                               const float4* __restrict__ eattr, int* __restrict__ cursor,
                               int* __restrict__ csr_src, uint4* __restrict__ csr_ea) {
  int e = blockIdx.x * blockDim.x + threadIdx.x;
  if (e < NE) {
    int d = dst[e];
    int pos = atomicAdd(&cursor[d], 1);
    csr_src[pos] = src[e];
    float4 a = eattr[2 * e];
    float4 b = eattr[2 * e + 1];
    uint4 o;
    o.x = (uint32)f2bf(a.x) | ((uint32)f2bf(a.y) << 16);
    o.y = (uint32)f2bf(a.z) | ((uint32)f2bf(a.w) << 16);
    o.z = (uint32)f2bf(b.x) | ((uint32)f2bf(b.y) << 16);
    o.w = (uint32)f2bf(b.z) | ((uint32)f2bf(b.w) << 16);
    csr_ea[pos] = o;
  }
}

// ---------------- node encoder: x[N,128] @ Wn[128,64] + bn (f32 + bf16 copies) -------
__global__ __launch_bounds__(256) void encoder_kernel(const float* __restrict__ x,
                                                      const float* __restrict__ Wn,
                                                      const float* __restrict__ bn,
                                                      float* __restrict__ outf,
                                                      ushort16* __restrict__ outb) {
  const int w = threadIdx.x >> 6, h = threadIdx.x & 63;
  const int v = blockIdx.x * 4 + w;
  __shared__ float sx[4][128];
  sx[w][h] = x[(size_t)v * 128 + h];
  sx[w][64 + h] = x[(size_t)v * 128 + 64 + h];
  __syncthreads();
  float acc = bn[h];
#pragma unroll 8
  for (int k = 0; k < 128; ++k) acc += sx[w][k] * Wn[k * 64 + h];
  outf[(size_t)v * 64 + h] = acc;
  outb[(size_t)v * 64 + h] = f2bf(acc);
}

// ---------------- GENConv: online per-channel segment softmax + fused MLP
//                  + fused epilogue relu(LayerNorm(.)) ----------------
__global__ __launch_bounds__(256) void conv_kernel(
    const float* __restrict__ inf,       // conv input f32 (own-row/residual reads)
    const ushort16* __restrict__ inb,    // conv input bf16 (gather table)
    const float* __restrict__ resid,     // outer residual (null layer 0)
    float* __restrict__ outp,            // new x f32 (may be null)
    float* __restrict__ lnoutf,          // relu(LN(new x)) f32
    ushort16* __restrict__ lnoutb,       // relu(LN(new x)) bf16 (may be null)
    const float* __restrict__ gLl, const float* __restrict__ bLl,
    const int* __restrict__ rowptr, const int* __restrict__ csr_src,
    const uint4* __restrict__ csr_ea,
    const float* __restrict__ We, const float* __restrict__ be,
    const float* __restrict__ tptr, int layer,
    const float* __restrict__ W1b, const float* __restrict__ b1b,
    const float* __restrict__ g1b, const float* __restrict__ c1b,
    const float* __restrict__ W2b, const float* __restrict__ b2b) {
  const int w = threadIdx.x >> 6, h = threadIdx.x & 63;
  const int v = blockIdx.x * 4 + w;
  const float* W1 = W1b + layer * 64 * 128;
  const float* b1 = b1b + layer * 128;
  const float* g1 = g1b + layer * 128;
  const float* c1 = c1b + layer * 128;
  const float* W2 = W2b + layer * 128 * 64;
  const float* b2 = b2b + layer * 64;
  const float t = tptr[layer];

  float we[8];
#pragma unroll
  for (int k = 0; k < 8; ++k) we[k] = We[k * 64 + h];
  const float beh = be[h];

  const int i0 = __builtin_amdgcn_readfirstlane(rowptr[v]);
  const int i1 = __builtin_amdgcn_readfirstlane(rowptr[v + 1]);
  float m = -1e30f, s = 0.f, o = 0.f;
  int i = i0;
  for (; i + 8 <= i1; i += 8) {
    int sidx[8];
    uint4 ev[8];
    float xv[8];
#pragma unroll
    for (int j = 0; j < 8; ++j) sidx[j] = csr_src[i + j];
#pragma unroll
    for (int j = 0; j < 8; ++j) ev[j] = csr_ea[i + j];
#pragma unroll
    for (int j = 0; j < 8; ++j) xv[j] = bfl((uint32)inb[(size_t)sidx[j] * 64 + h]);
    float g[8], l[8];
#pragma unroll
    for (int j = 0; j < 8; ++j) {
      float eh = beh + bfl(ev[j].x) * we[0] + bfh(ev[j].x) * we[1]
                     + bfl(ev[j].y) * we[2] + bfh(ev[j].y) * we[3]
                     + bfl(ev[j].z) * we[4] + bfh(ev[j].z) * we[5]
                     + bfl(ev[j].w) * we[6] + bfh(ev[j].w) * we[7];
      g[j] = fmaxf(xv[j] + eh, 0.f) + 1e-7f;
      l[j] = g[j] * t;
    }
    float mx = fmaxf(fmaxf(fmaxf(l[0], l[1]), fmaxf(l[2], l[3])),
                     fmaxf(fmaxf(l[4], l[5]), fmaxf(l[6], l[7])));
    float mn = fmaxf(m, mx);
    float c = __expf(m - mn);
    float ssum = 0.f, osum = 0.f;
#pragma unroll
    for (int j = 0; j < 8; ++j) {
      float p = __expf(l[j] - mn);
      ssum += p;
      osum += g[j] * p;
    }
    s = s * c + ssum;
    o = o * c + osum;
    m = mn;
  }
  for (; i < i1; ++i) {
    const int sv = csr_src[i];
    const uint4 e = csr_ea[i];
    const float xvv = bfl((uint32)inb[(size_t)sv * 64 + h]);
    float eh = beh + bfl(e.x) * we[0] + bfh(e.x) * we[1]
                   + bfl(e.y) * we[2] + bfh(e.y) * we[3]
                   + bfl(e.z) * we[4] + bfh(e.z) * we[5]
                   + bfl(e.w) * we[6] + bfh(e.w) * we[7];
    const float g = fmaxf(xvv + eh, 0.f) + 1e-7f;
    const float l = g * t;
    const float mn = fmaxf(m, l);
    const float c = __expf(m - mn);
    const float p = __expf(l - mn);
    s = s * c + p;
    o = o * c + g * p;
    m = mn;
  }
  float agg = o / (s + 1e-16f) + inf[(size_t)v * 64 + h];  // root residual (f32)

  // MLP: Linear(64,128) -> LN -> ReLU -> Linear(128,64)
  __shared__ float sh[4][64];
  __shared__ float sh2[4][128];
  sh[w][h] = agg;
  __syncthreads();
  float u0 = b1[h], u1 = b1[64 + h];
#pragma unroll 8
  for (int k = 0; k < 64; ++k) {
    float a = sh[w][k];
    u0 += a * W1[k * 128 + h];
    u1 += a * W1[k * 128 + 64 + h];
  }
  float mu = wave_sum(u0 + u1) * (1.f / 128.f);
  float d0 = u0 - mu, d1 = u1 - mu;
  float var = wave_sum(d0 * d0 + d1 * d1) * (1.f / 128.f);
  float r = rsqrtf(var + 1e-5f);
  float h0 = fmaxf(d0 * r * g1[h] + c1[h], 0.f);
  float h1 = fmaxf(d1 * r * g1[64 + h] + c1[64 + h], 0.f);
  sh2[w][h] = h0;
  sh2[w][64 + h] = h1;
  __syncthreads();
  float acc = b2[h];
#pragma unroll 8
  for (int k = 0; k < 128; ++k) acc += sh2[w][k] * W2[k * 64 + h];
  if (resid) acc += resid[(size_t)v * 64 + h];
  if (outp) outp[(size_t)v * 64 + h] = acc;

  // fused relu(LayerNorm(acc)) for the next stage
  float mu2 = wave_sum(acc) * (1.f / 64.f);
  float dd = acc - mu2;
  float vv = wave_sum(dd * dd) * (1.f / 64.f);
  float rr = rsqrtf(vv + 1e-5f);
  float lnv = fmaxf(dd * rr * gLl[h] + bLl[h], 0.f);
  lnoutf[(size_t)v * 64 + h] = lnv;
  if (lnoutb) lnoutb[(size_t)v * 64 + h] = f2bf(lnv);
}

// ---------------- head: (pre-activated input) @ Wo[64,112] + bo ----------------
__global__ __launch_bounds__(256) void head_kernel(const float* __restrict__ x,
                                                   const float* __restrict__ Wo,
                                                   const float* __restrict__ bo,
                                                   float* __restrict__ out) {
  const int w = threadIdx.x >> 6, h = threadIdx.x & 63;
  const int v = blockIdx.x * 4 + w;
  __shared__ float sh[4][64];
  sh[w][h] = x[(size_t)v * 64 + h];
  __syncthreads();
  float o0 = bo[h];
  float o1 = (h < 48) ? bo[64 + h] : 0.f;
  for (int k = 0; k < 64; ++k) {
    float a = sh[w][k];
    o0 += a * Wo[k * 112 + h];
    if (h < 48) o1 += a * Wo[k * 112 + 64 + h];
  }
  out[(size_t)v * 112 + h] = o0;
  if (h < 48) out[(size_t)v * 112 + 64 + h] = o1;
}

extern "C" void kernel_launch(void* const* d_in, const int* in_sizes, int n_in,
                              void* d_out, int out_size, void* d_ws, size_t ws_size,
                              hipStream_t stream) {
  const float* x     = (const float*)d_in[0];
  const int*   eidx  = (const int*)d_in[1];
  const float* eattr = (const float*)d_in[2];
  const float* Wn    = (const float*)d_in[3];
  const float* bn    = (const float*)d_in[4];
  const float* We    = (const float*)d_in[5];
  const float* be    = (const float*)d_in[6];
  const float* t     = (const float*)d_in[7];
  const float* W1    = (const float*)d_in[8];
  const float* b1    = (const float*)d_in[9];
  const float* g1    = (const float*)d_in[10];
  const float* c1    = (const float*)d_in[11];
  const float* W2    = (const float*)d_in[12];
  const float* b2    = (const float*)d_in[13];
  const float* gL    = (const float*)d_in[14];
  const float* bL    = (const float*)d_in[15];
  const float* Wo    = (const float*)d_in[16];
  const float* bo    = (const float*)d_in[17];
  float* out = (float*)d_out;

  const int* srcp = eidx;
  const int* dstp = eidx + NE;

  char* p = (char*)d_ws;
  auto alloc = [&](size_t bytes) {
    char* r = p;
    p += (bytes + 255) & ~(size_t)255;
    return r;
  };
  int*      deg     = (int*)alloc((size_t)NN * 4);
  int*      rowptr  = (int*)alloc((size_t)(NN + 1) * 4);
  int*      cursor  = (int*)alloc((size_t)NN * 4);
  int*      csr_src = (int*)alloc((size_t)NE * 4);
  uint4*    csr_ea  = (uint4*)alloc((size_t)NE * 16);
  float*    hAf     = (float*)alloc((size_t)NN * 64 * 4);
  ushort16* hAb     = (ushort16*)alloc((size_t)NN * 64 * 2);
  float*    hBf     = (float*)alloc((size_t)NN * 64 * 4);
  ushort16* hBb     = (ushort16*)alloc((size_t)NN * 64 * 2);
  float*    xA      = (float*)alloc((size_t)NN * 64 * 4);
  float*    xB      = (float*)alloc((size_t)NN * 64 * 4);

  // CSR build (per call — d_ws is re-poisoned before every launch)
  hipLaunchKernelGGL(zero_int_kernel, dim3((NN + 255) / 256), dim3(256), 0, stream, deg, NN);
  hipLaunchKernelGGL(count_kernel, dim3((NE + 255) / 256), dim3(256), 0, stream, dstp, deg);
  hipLaunchKernelGGL(scan_kernel, dim3(1), dim3(1024), 0, stream, deg, rowptr, cursor);
  hipLaunchKernelGGL(scatter_kernel, dim3((NE + 255) / 256), dim3(256), 0, stream, srcp, dstp,
                     (const float4*)eattr, cursor, csr_src, csr_ea);

  // encoder → h0 (conv0 input)
  hipLaunchKernelGGL(encoder_kernel, dim3(NN / 4), dim3(256), 0, stream, x, Wn, bn, hAf, hAb);

  // layer 0: x0 = conv(h0);             hB = relu(LN(x0, gL[1]))
  hipLaunchKernelGGL(conv_kernel, dim3(NN / 4), dim3(256), 0, stream, hAf, hAb,
                     (const float*)nullptr, xA, hBf, hBb, gL + 64, bL + 64, rowptr, csr_src,
                     csr_ea, We, be, t, 0, W1, b1, g1, c1, W2, b2);
  // layer 1: x1 = x0 + conv(hB);        hA = relu(LN(x1, gL[2]))
  hipLaunchKernelGGL(conv_kernel, dim3(NN / 4), dim3(256), 0, stream, hBf, hBb, xA, xB, hAf,
                     hAb, gL + 128, bL + 128, rowptr, csr_src, csr_ea, We, be, t, 1, W1, b1,
                     g1, c1, W2, b2);
  // layer 2: x2 = x1 + conv(hA);        hB = relu(LN(x2, gL[3]))
  hipLaunchKernelGGL(conv_kernel, dim3(NN / 4), dim3(256), 0, stream, hAf, hAb, xB, xA, hBf,
                     hBb, gL + 192, bL + 192, rowptr, csr_src, csr_ea, We, be, t, 2, W1, b1,
                     g1, c1, W2, b2);
  // layer 3: x3 = x2 + conv(hB);        hA = relu(LN(x3, gL[0])) → head input
  hipLaunchKernelGGL(conv_kernel, dim3(NN / 4), dim3(256), 0, stream, hBf, hBb, xA,
                     (float*)nullptr, hAf, (ushort16*)nullptr, gL, bL, rowptr, csr_src, csr_ea,
                     We, be, t, 3, W1, b1, g1, c1, W2, b2);

  // head
  hipLaunchKernelGGL(head_kernel, dim3(NN / 4), dim3(256), 0, stream, hAf, Wo, bo, out);
}

// Round 12
// 695.688 us; speedup vs baseline: 1.3703x; 1.3703x over previous
//
#include <hip/hip_runtime.h>

#define NN 50000
#define NE 800000
#define NB 196  // ceil(NN/256)

typedef unsigned int uint32;
typedef unsigned short ushort16;
typedef _Float16 half2v __attribute__((ext_vector_type(2)));

__device__ __forceinline__ float wave_sum(float v) {
#pragma unroll
  for (int off = 32; off > 0; off >>= 1) v += __shfl_xor(v, off, 64);
  return v;
}
__device__ __forceinline__ float bfl(uint32 u) {  // bf16 (low 16) -> f32
  union { uint32 u; float f; } c; c.u = u << 16; return c.f;
}
__device__ __forceinline__ ushort16 f2bf(float f) {  // RNE pack
  union { float f; uint32 u; } c; c.f = f;
  uint32 r = c.u + 0x7fffu + ((c.u >> 16) & 1u);
  return (ushort16)(r >> 16);
}
__device__ __forceinline__ uint32 pk2h(float a, float b) {  // two f32 -> packed f16x2
  union { half2v h; uint32 u; } c;
  c.h[0] = (_Float16)a; c.h[1] = (_Float16)b;
  return c.u;
}
__device__ __forceinline__ float dot2(uint32 a, uint32 b, float acc) {
  union { uint32 u; half2v h; } ca, cb;
  ca.u = a; cb.u = b;
#if __has_builtin(__builtin_amdgcn_fdot2)
  return __builtin_amdgcn_fdot2(ca.h, cb.h, acc, false);
#else
  return acc + (float)ca.h[0] * (float)cb.h[0] + (float)ca.h[1] * (float)cb.h[1];
#endif
}

// ---------------- weight pre-pack (f32 -> f16 k-pairs, padded LDS layouts) ----------
// Wcat[l] (8288 u32): [0,4128) W1p: i*129+j, pair(W1[2i][j],W1[2i+1][j]), i<32,j<128
//                     [4128,8288) W2p: i*65+j, pair(W2[2i][j],W2[2i+1][j]), i<64,j<64
// Wnp (4160 u32): i*65+j from Wn[2i][j], i<64,j<64
// Wop (3616 u32): i*113+j from Wo[2i][j], i<32,j<112
__global__ __launch_bounds__(256) void pack_kernel(const float* __restrict__ W1,
                                                   const float* __restrict__ W2,
                                                   const float* __restrict__ Wn,
                                                   const float* __restrict__ Wo,
                                                   uint32* __restrict__ Wcat,
                                                   uint32* __restrict__ Wnp,
                                                   uint32* __restrict__ Wop) {
  int id = blockIdx.x * 256 + threadIdx.x;
  if (id < 16384) {
    int l = id >> 12, r = id & 4095, i = r >> 7, j = r & 127;
    const float* w = W1 + l * 8192;
    Wcat[l * 8288 + i * 129 + j] = pk2h(w[(2 * i) * 128 + j], w[(2 * i + 1) * 128 + j]);
  } else if (id < 32768) {
    int q = id - 16384;
    int l = q >> 12, r = q & 4095, i = r >> 6, j = r & 63;
    const float* w = W2 + l * 8192;
    Wcat[l * 8288 + 4128 + i * 65 + j] = pk2h(w[(2 * i) * 64 + j], w[(2 * i + 1) * 64 + j]);
  } else if (id < 36864) {
    int r = id - 32768, i = r >> 6, j = r & 63;
    Wnp[i * 65 + j] = pk2h(Wn[(2 * i) * 64 + j], Wn[(2 * i + 1) * 64 + j]);
  } else if (id < 40448) {
    int r = id - 36864, i = r / 112, j = r - i * 112;
    Wop[i * 113 + j] = pk2h(Wo[(2 * i) * 112 + j], Wo[(2 * i + 1) * 112 + j]);
  }
}

// ---------------- CSR build ----------------
__global__ void zero_int_kernel(int* __restrict__ p, int n) {
  int i = blockIdx.x * blockDim.x + threadIdx.x;
  if (i < n) p[i] = 0;
}

__global__ void count_kernel(const int* __restrict__ dst, int* __restrict__ deg) {
  int e = blockIdx.x * blockDim.x + threadIdx.x;
  if (e < NE) atomicAdd(&deg[dst[e]], 1);
}

__global__ __launch_bounds__(256) void scanA_kernel(const int* __restrict__ deg,
                                                    int* __restrict__ bsum) {
  __shared__ int red[256];
  int t = threadIdx.x, i = blockIdx.x * 256 + t;
  red[t] = (i < NN) ? deg[i] : 0;
  __syncthreads();
  for (int off = 128; off > 0; off >>= 1) {
    if (t < off) red[t] += red[t + off];
    __syncthreads();
  }
  if (t == 0) bsum[blockIdx.x] = red[0];
}

__global__ __launch_bounds__(256) void scanB_kernel(const int* __restrict__ bsum,
                                                    int* __restrict__ bbase,
                                                    int* __restrict__ rowptr) {
  __shared__ int sc[256];
  int t = threadIdx.x;
  int mine = (t < NB) ? bsum[t] : 0;
  sc[t] = mine;
  __syncthreads();
  for (int off = 1; off < 256; off <<= 1) {
    int val = sc[t];
    int add = (t >= off) ? sc[t - off] : 0;
    __syncthreads();
    sc[t] = val + add;
    __syncthreads();
  }
  if (t < NB) bbase[t] = sc[t] - mine;
  if (t == NB - 1) rowptr[NN] = sc[t];
}

__global__ __launch_bounds__(256) void scanC_kernel(const int* __restrict__ deg,
                                                    const int* __restrict__ bbase,
                                                    int* __restrict__ rowptr,
                                                    int* __restrict__ cursor) {
  __shared__ int sc[256];
  int t = threadIdx.x, i = blockIdx.x * 256 + t;
  int d = (i < NN) ? deg[i] : 0;
  sc[t] = d;
  __syncthreads();
  for (int off = 1; off < 256; off <<= 1) {
    int val = sc[t];
    int add = (t >= off) ? sc[t - off] : 0;
    __syncthreads();
    sc[t] = val + add;
    __syncthreads();
  }
  if (i < NN) {
    int excl = bbase[blockIdx.x] + sc[t] - d;
    rowptr[i] = excl;
    cursor[i] = excl;
  }
}

// scatter into CSR order; edge_attr packed to f16x8 (16 B/edge)
__global__ void scatter_kernel(const int* __restrict__ src, const int* __restrict__ dst,
                               const float4* __restrict__ eattr, int* __restrict__ cursor,
                               int* __restrict__ csr_src, uint4* __restrict__ csr_ea) {
  int e = blockIdx.x * blockDim.x + threadIdx.x;
  if (e < NE) {
    int d = dst[e];
    int pos = atomicAdd(&cursor[d], 1);
    csr_src[pos] = src[e];
    float4 a = eattr[2 * e];
    float4 b = eattr[2 * e + 1];
    csr_ea[pos] = make_uint4(pk2h(a.x, a.y), pk2h(a.z, a.w), pk2h(b.x, b.y), pk2h(b.z, b.w));
  }
}

// ---------------- node encoder: x[N,128] @ Wn[128,64] + bn ----------------
// Activation pairs live in registers (lane k holds pair k); broadcast via readlane.
__global__ __launch_bounds__(512) void encoder_kernel(const float2* __restrict__ x2,
                                                      const uint32* __restrict__ Wnp,
                                                      const float* __restrict__ bn,
                                                      float* __restrict__ outf,
                                                      ushort16* __restrict__ outb) {
  __shared__ __align__(16) uint32 sWn[4160];
  const int wv = threadIdx.x >> 6, h = threadIdx.x & 63;
  const int v = blockIdx.x * 8 + wv;
  {
    const uint4* ws = (const uint4*)Wnp;
    uint4* d = (uint4*)sWn;
    for (int idx = threadIdx.x; idx < 1040; idx += 512) d[idx] = ws[idx];
  }
  __syncthreads();
  float2 xp = x2[(size_t)v * 64 + h];
  uint32 xpk = pk2h(xp.x, xp.y);  // lane k: pair (x[2k], x[2k+1])
  float a0 = bn[h], a1 = 0.f;
#pragma unroll
  for (int k = 0; k < 64; k += 2) {
    a0 = dot2(__shfl(xpk, k, 64), sWn[k * 65 + h], a0);
    a1 = dot2(__shfl(xpk, k + 1, 64), sWn[(k + 1) * 65 + h], a1);
  }
  float acc = a0 + a1;
  outf[(size_t)v * 64 + h] = acc;
  outb[(size_t)v * 64 + h] = f2bf(acc);
}

// ---------------- GENConv: online softmax agg + f16 MLP (LDS weights only) + LN ------
__global__ __launch_bounds__(512) void conv_kernel(
    const float* __restrict__ inf, const ushort16* __restrict__ inb,
    const float* __restrict__ resid, float* __restrict__ outp,
    float* __restrict__ lnoutf, ushort16* __restrict__ lnoutb,
    const float* __restrict__ gLl, const float* __restrict__ bLl,
    const int* __restrict__ rowptr, const int* __restrict__ csr_src,
    const uint4* __restrict__ csr_ea, const uint32* __restrict__ Wcat,
    const float* __restrict__ We, const float* __restrict__ be,
    const float* __restrict__ tptr, int layer,
    const float* __restrict__ b1b, const float* __restrict__ g1b,
    const float* __restrict__ c1b, const float* __restrict__ b2b) {
  __shared__ __align__(16) uint32 sW[8288];  // [0,4128) W1p, [4128,8288) W2p
  const int wv = threadIdx.x >> 6, h = threadIdx.x & 63;
  const int v = blockIdx.x * 8 + wv;
  {
    const uint4* ws = (const uint4*)(Wcat + layer * 8288);
    uint4* d = (uint4*)sW;
    for (int idx = threadIdx.x; idx < 2072; idx += 512) d[idx] = ws[idx];
  }
  __syncthreads();  // weights staged; waves fully independent from here on

  const float t = tptr[layer];
  const float beh = be[h];
  const uint32 wep0 = pk2h(We[h], We[64 + h]);
  const uint32 wep1 = pk2h(We[128 + h], We[192 + h]);
  const uint32 wep2 = pk2h(We[256 + h], We[320 + h]);
  const uint32 wep3 = pk2h(We[384 + h], We[448 + h]);

  const int i0 = __builtin_amdgcn_readfirstlane(rowptr[v]);
  const int i1 = __builtin_amdgcn_readfirstlane(rowptr[v + 1]);
  float m = -1e30f, s = 0.f, o = 0.f;
  int i = i0;
  for (; i + 8 <= i1; i += 8) {
    uint32 off[8];
    uint4 ev[8];
    float xv[8];
#pragma unroll
    for (int j = 0; j < 8; ++j) off[j] = (uint32)(csr_src[i + j] * 64 + h);
#pragma unroll
    for (int j = 0; j < 8; ++j) ev[j] = csr_ea[i + j];
#pragma unroll
    for (int j = 0; j < 8; ++j) xv[j] = bfl((uint32)inb[off[j]]);
    float g[8], l[8];
#pragma unroll
    for (int j = 0; j < 8; ++j) {
      float eh = dot2(ev[j].x, wep0,
                 dot2(ev[j].y, wep1, dot2(ev[j].z, wep2, dot2(ev[j].w, wep3, beh))));
      g[j] = fmaxf(xv[j] + eh, 0.f) + 1e-7f;
      l[j] = g[j] * t;
    }
    float mx = fmaxf(fmaxf(fmaxf(l[0], l[1]), fmaxf(l[2], l[3])),
                     fmaxf(fmaxf(l[4], l[5]), fmaxf(l[6], l[7])));
    float mn = fmaxf(m, mx);
    float c = __expf(m - mn);
    float ssum = 0.f, osum = 0.f;
#pragma unroll
    for (int j = 0; j < 8; ++j) {
      float p = __expf(l[j] - mn);
      ssum += p;
      osum += g[j] * p;
    }
    s = s * c + ssum;
    o = o * c + osum;
    m = mn;
  }
  for (; i < i1; ++i) {
    const uint32 off = (uint32)(csr_src[i] * 64 + h);
    const uint4 e = csr_ea[i];
    const float xvv = bfl((uint32)inb[off]);
    float eh = dot2(e.x, wep0, dot2(e.y, wep1, dot2(e.z, wep2, dot2(e.w, wep3, beh))));
    const float g = fmaxf(xvv + eh, 0.f) + 1e-7f;
    const float l = g * t;
    const float mn = fmaxf(m, l);
    const float c = __expf(m - mn);
    const float p = __expf(l - mn);
    s = s * c + p;
    o = o * c + g * p;
    m = mn;
  }
  float agg = o / (s + 1e-16f) + inf[(size_t)v * 64 + h];  // root residual (f32)

  const float* b1 = b1b + layer * 128;
  const float* g1 = g1b + layer * 128;
  const float* c1 = c1b + layer * 128;
  const float* b2 = b2b + layer * 64;

  // Linear(64,128): pair (2k,2k+1) packed in even lane 2k, broadcast by readlane
  uint32 aggpk = pk2h(agg, __shfl_xor(agg, 1, 64));  // valid in even lanes
  float u0 = b1[h], u1 = b1[64 + h];
#pragma unroll
  for (int k = 0; k < 32; ++k) {
    uint32 a = __shfl(aggpk, 2 * k, 64);
    u0 = dot2(a, sW[k * 129 + h], u0);
    u1 = dot2(a, sW[k * 129 + 64 + h], u1);
  }
  float mu = wave_sum(u0 + u1) * (1.f / 128.f);
  float d0 = u0 - mu, d1 = u1 - mu;
  float var = wave_sum(d0 * d0 + d1 * d1) * (1.f / 128.f);
  float r = rsqrtf(var + 1e-5f);
  float h0 = fmaxf(d0 * r * g1[h] + c1[h], 0.f);
  float h1 = fmaxf(d1 * r * g1[64 + h] + c1[64 + h], 0.f);

  // Linear(128,64): hidden cols (2m,2m+1) in pA (even lane 2m), (64+2m,64+2m+1) in pB
  uint32 pA = pk2h(h0, __shfl_xor(h0, 1, 64));
  uint32 pB = pk2h(h1, __shfl_xor(h1, 1, 64));
  const uint32* sW2u = sW + 4128;
  float acA = b2[h], acB = 0.f;
#pragma unroll
  for (int mi = 0; mi < 32; ++mi) {
    uint32 aA = __shfl(pA, 2 * mi, 64);
    uint32 aB = __shfl(pB, 2 * mi, 64);
    acA = dot2(aA, sW2u[mi * 65 + h], acA);
    acB = dot2(aB, sW2u[(32 + mi) * 65 + h], acB);
  }
  float acc = acA + acB;
  if (resid) acc += resid[(size_t)v * 64 + h];
  if (outp) outp[(size_t)v * 64 + h] = acc;

  // fused relu(LayerNorm(acc)) for the next stage
  float mu2 = wave_sum(acc) * (1.f / 64.f);
  float dd = acc - mu2;
  float vv = wave_sum(dd * dd) * (1.f / 64.f);
  float rr = rsqrtf(vv + 1e-5f);
  float lnv = fmaxf(dd * rr * gLl[h] + bLl[h], 0.f);
  lnoutf[(size_t)v * 64 + h] = lnv;
  if (lnoutb) lnoutb[(size_t)v * 64 + h] = f2bf(lnv);
}

// ---------------- head: in @ Wo[64,112] + bo ----------------
__global__ __launch_bounds__(512) void head_kernel(const float2* __restrict__ in2,
                                                   const uint32* __restrict__ Wop,
                                                   const float* __restrict__ bo,
                                                   float* __restrict__ out) {
  __shared__ __align__(16) uint32 sWo[3616];
  const int wv = threadIdx.x >> 6, h = threadIdx.x & 63;
  const int v = blockIdx.x * 8 + wv;
  {
    const uint4* ws = (const uint4*)Wop;
    uint4* d = (uint4*)sWo;
    for (int idx = threadIdx.x; idx < 904; idx += 512) d[idx] = ws[idx];
  }
  __syncthreads();
  uint32 ipk = 0;
  if (h < 32) {
    float2 p = in2[(size_t)v * 32 + h];
    ipk = pk2h(p.x, p.y);  // lane k<32: pair (in[2k], in[2k+1])
  }
  const int hh = (h < 48) ? h : 47;  // safe index for masked second output
  float o0 = bo[h];
  float o1 = (h < 48) ? bo[64 + h] : 0.f;
#pragma unroll
  for (int k = 0; k < 32; ++k) {
    uint32 a = __shfl(ipk, k, 64);
    o0 = dot2(a, sWo[k * 113 + h], o0);
    o1 = dot2(a, sWo[k * 113 + 64 + hh], o1);
  }
  out[(size_t)v * 112 + h] = o0;
  if (h < 48) out[(size_t)v * 112 + 64 + h] = o1;
}

extern "C" void kernel_launch(void* const* d_in, const int* in_sizes, int n_in,
                              void* d_out, int out_size, void* d_ws, size_t ws_size,
                              hipStream_t stream) {
  const float* x     = (const float*)d_in[0];
  const int*   eidx  = (const int*)d_in[1];
  const float* eattr = (const float*)d_in[2];
  const float* Wn    = (const float*)d_in[3];
  const float* bn    = (const float*)d_in[4];
  const float* We    = (const float*)d_in[5];
  const float* be    = (const float*)d_in[6];
  const float* t     = (const float*)d_in[7];
  const float* W1    = (const float*)d_in[8];
  const float* b1    = (const float*)d_in[9];
  const float* g1    = (const float*)d_in[10];
  const float* c1    = (const float*)d_in[11];
  const float* W2    = (const float*)d_in[12];
  const float* b2    = (const float*)d_in[13];
  const float* gL    = (const float*)d_in[14];
  const float* bL    = (const float*)d_in[15];
  const float* Wo    = (const float*)d_in[16];
  const float* bo    = (const float*)d_in[17];
  float* out = (float*)d_out;

  const int* srcp = eidx;
  const int* dstp = eidx + NE;

  char* p = (char*)d_ws;
  auto alloc = [&](size_t bytes) {
    char* r = p;
    p += (bytes + 255) & ~(size_t)255;
    return r;
  };
  int*      deg     = (int*)alloc((size_t)NN * 4);
  int*      rowptr  = (int*)alloc((size_t)(NN + 1) * 4);
  int*      cursor  = (int*)alloc((size_t)NN * 4);
  int*      bsum    = (int*)alloc((size_t)NB * 4);
  int*      bbase   = (int*)alloc((size_t)NB * 4);
  int*      csr_src = (int*)alloc((size_t)NE * 4);
  uint4*    csr_ea  = (uint4*)alloc((size_t)NE * 16);
  uint32*   Wcat    = (uint32*)alloc((size_t)4 * 8288 * 4);
  uint32*   Wnp     = (uint32*)alloc((size_t)4160 * 4);
  uint32*   Wop     = (uint32*)alloc((size_t)3616 * 4);
  float*    hAf     = (float*)alloc((size_t)NN * 64 * 4);
  ushort16* hAb     = (ushort16*)alloc((size_t)NN * 64 * 2);
  float*    hBf     = (float*)alloc((size_t)NN * 64 * 4);
  ushort16* hBb     = (ushort16*)alloc((size_t)NN * 64 * 2);
  float*    xA      = (float*)alloc((size_t)NN * 64 * 4);
  float*    xB      = (float*)alloc((size_t)NN * 64 * 4);

  // weight pre-pack (f16)
  hipLaunchKernelGGL(pack_kernel, dim3(158), dim3(256), 0, stream, W1, W2, Wn, Wo, Wcat, Wnp,
                     Wop);

  // CSR build
  hipLaunchKernelGGL(zero_int_kernel, dim3((NN + 255) / 256), dim3(256), 0, stream, deg, NN);
  hipLaunchKernelGGL(count_kernel, dim3((NE + 255) / 256), dim3(256), 0, stream, dstp, deg);
  hipLaunchKernelGGL(scanA_kernel, dim3(NB), dim3(256), 0, stream, deg, bsum);
  hipLaunchKernelGGL(scanB_kernel, dim3(1), dim3(256), 0, stream, bsum, bbase, rowptr);
  hipLaunchKernelGGL(scanC_kernel, dim3(NB), dim3(256), 0, stream, deg, bbase, rowptr, cursor);
  hipLaunchKernelGGL(scatter_kernel, dim3((NE + 255) / 256), dim3(256), 0, stream, srcp, dstp,
                     (const float4*)eattr, cursor, csr_src, csr_ea);

  // encoder
  hipLaunchKernelGGL(encoder_kernel, dim3(NN / 8), dim3(512), 0, stream, (const float2*)x, Wnp,
                     bn, hAf, hAb);

  // layer 0
  hipLaunchKernelGGL(conv_kernel, dim3(NN / 8), dim3(512), 0, stream, hAf, hAb,
                     (const float*)nullptr, xA, hBf, hBb, gL + 64, bL + 64, rowptr, csr_src,
                     (const uint4*)csr_ea, Wcat, We, be, t, 0, b1, g1, c1, b2);
  // layer 1
  hipLaunchKernelGGL(conv_kernel, dim3(NN / 8), dim3(512), 0, stream, hBf, hBb, xA, xB, hAf,
                     hAb, gL + 128, bL + 128, rowptr, csr_src, (const uint4*)csr_ea, Wcat, We,
                     be, t, 1, b1, g1, c1, b2);
  // layer 2
  hipLaunchKernelGGL(conv_kernel, dim3(NN / 8), dim3(512), 0, stream, hAf, hAb, xB, xA, hBf,
                     hBb, gL + 192, bL + 192, rowptr, csr_src, (const uint4*)csr_ea, Wcat, We,
                     be, t, 2, b1, g1, c1, b2);
  // layer 3 (final x not needed; LN feeds head)
  hipLaunchKernelGGL(conv_kernel, dim3(NN / 8), dim3(512), 0, stream, hBf, hBb, xA,
                     (float*)nullptr, hAf, (ushort16*)nullptr, gL, bL, rowptr, csr_src,
                     (const uint4*)csr_ea, Wcat, We, be, t, 3, b1, g1, c1, b2);

  // head
  hipLaunchKernelGGL(head_kernel, dim3(NN / 8), dim3(512), 0, stream, (const float2*)hAf, Wop,
                     bo, out);
}